// Round 2
// baseline (848.889 us; speedup 1.0000x reference)
//
#include <hip/hip_runtime.h>
#include <hip/hip_bf16.h>

typedef __attribute__((ext_vector_type(8))) short bf16x8;
typedef __attribute__((ext_vector_type(4))) float f32x4;
typedef __attribute__((ext_vector_type(8))) unsigned short ushort8;

__device__ __forceinline__ float bf2f(unsigned short u) {
  union { unsigned int i; float f; } v; v.i = ((unsigned int)u) << 16; return v.f;
}
__device__ __forceinline__ unsigned short f2bf(float f) {
  __hip_bfloat16 h = __float2bfloat16(f);
  unsigned short u; __builtin_memcpy(&u, &h, 2); return u;
}

// ---------------------------------------------------------------------------
// Kernel P: convert qkv_w (384x128) and proj_w (128x128) fp32 -> bf16 in ws
// ---------------------------------------------------------------------------
__global__ void k_prep(const float* __restrict__ qkvw, const float* __restrict__ projw,
                       unsigned short* __restrict__ qkvw_bf,
                       unsigned short* __restrict__ projw_bf) {
  int t = blockIdx.x * 256 + threadIdx.x;   // 16384 threads x 4 elements
  int i = t * 4;
  const float* src;
  unsigned short* dst;
  int idx;
  if (i < 49152) { src = qkvw; dst = qkvw_bf; idx = i; }
  else           { src = projw; dst = projw_bf; idx = i - 49152; }
  float4 v = *(const float4*)(src + idx);
  union { unsigned short u[4]; uint2 v2; } o;
  o.u[0] = f2bf(v.x); o.u[1] = f2bf(v.y); o.u[2] = f2bf(v.z); o.u[3] = f2bf(v.w);
  *(uint2*)(dst + idx) = o.v2;
}

// ---------------------------------------------------------------------------
// Kernel B: padded bias table  biasp[h][64][64]; -1e30 outside 49x49
// ---------------------------------------------------------------------------
__global__ void k_bias(const float* __restrict__ bt,
                       const int* __restrict__ ri,
                       float* __restrict__ bp) {
  int t = blockIdx.x * 256 + threadIdx.x;   // 16384
  int hq = t >> 12;
  int q  = (t >> 6) & 63;
  int k  = t & 63;
  float v = -1e30f;
  if (q < 49 && k < 49) v = bt[ri[q * 49 + k] * 4 + hq];
  bp[t] = v;
}

// ---------------------------------------------------------------------------
// Kernel M: padded mask table  maskp[wrem][64][64]; -1e30 outside 49x49
// ---------------------------------------------------------------------------
__global__ void k_mask(const float* __restrict__ am, float* __restrict__ mp) {
  int t = blockIdx.x * 256 + threadIdx.x;   // 1048576
  int w = t >> 12;
  int q = (t >> 6) & 63;
  int k = t & 63;
  float v = -1e30f;
  if (q < 49 && k < 49) v = am[w * 2401 + q * 49 + k];
  mp[t] = v;
}

// ---------------------------------------------------------------------------
// Kernel 1: LayerNorm over C + cyclic shift (-3,-3) + window partition
// single pass: 128 channels held in VGPRs
// ---------------------------------------------------------------------------
__global__ __launch_bounds__(256, 3) void k_ln(const float* __restrict__ x,
                                               const float* __restrict__ nw,
                                               const float* __restrict__ nb,
                                               unsigned short* __restrict__ xw) {
  int p = blockIdx.x * 256 + threadIdx.x;   // 0 .. 401407 (exact)
  int b = p / 12544;
  int r = p - b * 12544;
  int hh = r / 112;
  int wp = r - hh * 112;
  const float* bx = x + (size_t)b * 1605632 + r;  // b*C*H*W + h*W + w

  float v[128];
  float s0 = 0.f, s1 = 0.f, q0 = 0.f, q1 = 0.f;
  #pragma unroll
  for (int c = 0; c < 128; c += 2) {
    float a = bx[(size_t)c * 12544];
    float bb = bx[(size_t)(c + 1) * 12544];
    v[c] = a; v[c + 1] = bb;
    s0 += a; q0 += a * a;
    s1 += bb; q1 += bb * bb;
  }
  float mu = (s0 + s1) * 0.0078125f;
  float var = (q0 + q1) * 0.0078125f - mu * mu;
  float rstd = rsqrtf(var + 1e-5f);

  // destination (shifted coords): h' = (hh-3) mod 112
  int h2 = hh + 109; if (h2 >= 112) h2 -= 112;
  int w2 = wp + 109; if (w2 >= 112) w2 -= 112;
  int wh = h2 / 7, ii = h2 - wh * 7;
  int ww = w2 / 7, jj = w2 - ww * 7;
  int winl = (b * 16 + wh) * 16 + ww;
  unsigned short* dst = xw + ((size_t)winl * 49 + ii * 7 + jj) * 128;

  #pragma unroll
  for (int g = 0; g < 4; ++g) {
    unsigned int pk[16];
    #pragma unroll
    for (int q = 0; q < 16; ++q) {
      int c = g * 32 + 2 * q;
      float y0 = (v[c] - mu) * rstd * nw[c]         + nb[c];
      float y1 = (v[c + 1] - mu) * rstd * nw[c + 1] + nb[c + 1];
      pk[q] = (unsigned int)f2bf(y0) | ((unsigned int)f2bf(y1) << 16);
    }
    uint4* d4 = (uint4*)(dst + g * 32);
    #pragma unroll
    for (int k = 0; k < 4; ++k)
      d4[k] = make_uint4(pk[4 * k], pk[4 * k + 1], pk[4 * k + 2], pk[4 * k + 3]);
  }
}

// ---------------------------------------------------------------------------
// Kernel 2: fused window attention. 1 block = 1 window, wave h = head h.
// LDS 48 KiB -> 3 blocks/CU. All LDS tiles XOR-swizzled at 16B granularity.
// Per head block (12288 B at h*12288):
//   Q [64 tok][64B]  @0     (swz chunk ^ ((row>>1)&3))
//   K [64 tok][64B]  @4096
//   V^T [32 dim][128B] @8192 (swz chunk ^ (row&7))
//   P [64 q][128B]   @0 overlays Q+K (swz chunk ^ (row&7))
//   O [64 tok][64B]  @0 overlays P rows 0..31 (safe: pf[tt] read before store)
// X staging [64][256B] @0 (swz chunk^ (row&7)), dead after xf loads.
// Operand-swapped MFMAs give vectorized (8B) fragment stores everywhere.
// ---------------------------------------------------------------------------
__global__ __launch_bounds__(256, 3) void k_attn(
    const unsigned short* __restrict__ xw,
    const unsigned short* __restrict__ qkvw,
    const float* __restrict__ qkvb,
    const unsigned short* __restrict__ projw,
    const float* __restrict__ projb,
    const float* __restrict__ biasp,
    const float* __restrict__ maskp,
    unsigned short* __restrict__ yw) {
  __shared__ __attribute__((aligned(16))) char smem[49152];
  const int tid  = threadIdx.x;
  const int lane = tid & 63;
  const int h    = tid >> 6;
  const int m15  = lane & 15;
  const int quad = lane >> 4;
  const int win  = blockIdx.x;
  const int b    = win >> 8;
  const int wrem = win & 255;
  const int wh   = wrem >> 4;
  const int ww   = wrem & 15;
  const f32x4 fz = {0.f, 0.f, 0.f, 0.f};

  // ---- stage X window (49x128 bf16 -> 64 rows x 256B swizzled, zero pad) ----
  {
    const uint4* gsrc = (const uint4*)(xw + (size_t)win * 6272);
    #pragma unroll
    for (int it = 0; it < 4; ++it) {
      int cc = tid + it * 256;                 // 16B chunk index, 0..1023
      int row = cc >> 4, col = cc & 15;
      uint4 v = make_uint4(0u, 0u, 0u, 0u);
      if (cc < 784) v = gsrc[cc];
      *(uint4*)(smem + row * 256 + ((col ^ (row & 7)) << 4)) = v;
    }
  }
  __syncthreads();

  // ---- X fragments (dual-role: A-frag row=token / B-frag col=token) ----
  bf16x8 xf[4][4];
  #pragma unroll
  for (int mt = 0; mt < 4; ++mt) {
    int row = mt * 16 + m15;
    #pragma unroll
    for (int kt = 0; kt < 4; ++kt)
      xf[mt][kt] = *(const bf16x8*)(smem + row * 256 + (((kt * 4 + quad) ^ (row & 7)) << 4));
  }
  __syncthreads();

  char* const hb  = smem + h * 12288;
  char* const qpb = hb;           // Q, then P, then O
  char* const kpb = hb + 4096;    // K
  char* const vpb = hb + 8192;    // V^T

  // ---- Q,K: swapped mfma(W,X) -> lane holds token=m15, 4 dims -> 8B store ----
  #pragma unroll
  for (int g = 0; g < 2; ++g) {
    char* const dst = g ? kpb : qpb;
    #pragma unroll
    for (int sp = 0; sp < 2; ++sp) {
      int nt = g * 8 + 2 * h + sp;
      bf16x8 wfr[4];
      #pragma unroll
      for (int kt = 0; kt < 4; ++kt)
        wfr[kt] = *(const bf16x8*)(qkvw + (nt * 16 + m15) * 128 + kt * 32 + quad * 8);
      float4 b4 = *(const float4*)(qkvb + nt * 16 + quad * 4);
      #pragma unroll
      for (int mt = 0; mt < 4; ++mt) {
        f32x4 acc = fz;
        #pragma unroll
        for (int kt = 0; kt < 4; ++kt)
          acc = __builtin_amdgcn_mfma_f32_16x16x32_bf16(wfr[kt], xf[mt][kt], acc, 0, 0, 0);
        int row = mt * 16 + m15;
        union { unsigned short u[4]; uint2 v2; } o;
        o.u[0] = f2bf(acc[0] + b4.x); o.u[1] = f2bf(acc[1] + b4.y);
        o.u[2] = f2bf(acc[2] + b4.z); o.u[3] = f2bf(acc[3] + b4.w);
        int chunk = sp * 2 + (quad >> 1);
        *(uint2*)(dst + row * 64 + ((chunk ^ ((row >> 1) & 3)) << 4) + (quad & 1) * 8) = o.v2;
      }
    }
  }
  // ---- V: normal mfma(X,W) -> lane holds dim=m15, 4 tokens -> 8B store ----
  #pragma unroll
  for (int sp = 0; sp < 2; ++sp) {
    int nt = 16 + 2 * h + sp;
    bf16x8 wfr[4];
    #pragma unroll
    for (int kt = 0; kt < 4; ++kt)
      wfr[kt] = *(const bf16x8*)(qkvw + (nt * 16 + m15) * 128 + kt * 32 + quad * 8);
    float bias = qkvb[nt * 16 + m15];
    int dsub = sp * 16 + m15;
    #pragma unroll
    for (int mt = 0; mt < 4; ++mt) {
      f32x4 acc = fz;
      #pragma unroll
      for (int kt = 0; kt < 4; ++kt)
        acc = __builtin_amdgcn_mfma_f32_16x16x32_bf16(xf[mt][kt], wfr[kt], acc, 0, 0, 0);
      union { unsigned short u[4]; uint2 v2; } o;
      #pragma unroll
      for (int rr = 0; rr < 4; ++rr) o.u[rr] = f2bf(acc[rr] + bias);
      int chunk = mt * 2 + (quad >> 1);
      *(uint2*)(vpb + dsub * 128 + ((chunk ^ (dsub & 7)) << 4) + (quad & 1) * 8) = o.v2;
    }
  }

  // ---- S^T = K Q^T : lane holds q = m15 (per mt tile), 16 k-values ----
  bf16x8 qf[4], kf[4];
  #pragma unroll
  for (int t = 0; t < 4; ++t) {
    int row = t * 16 + m15;
    int sw = ((row >> 1) & 3) << 4;
    qf[t] = *(const bf16x8*)(qpb + row * 64 + ((quad << 4) ^ sw));
    kf[t] = *(const bf16x8*)(kpb + row * 64 + ((quad << 4) ^ sw));
  }
  f32x4 st[4][4];   // st[nt][mt]: rows = k-tokens (nt), cols = q-tokens (mt)
  #pragma unroll
  for (int nt = 0; nt < 4; ++nt)
    #pragma unroll
    for (int mt = 0; mt < 4; ++mt)
      st[nt][mt] = __builtin_amdgcn_mfma_f32_16x16x32_bf16(kf[nt], qf[mt], fz, 0, 0, 0);

  // ---- softmax over k (cross-quad reduce only), P stored as 8B vectors ----
  const float* bp = biasp + h * 4096;
  const float* mp = maskp + wrem * 4096;
  #pragma unroll
  for (int mt = 0; mt < 4; ++mt) {
    int q = mt * 16 + m15;
    float sv[16];
    #pragma unroll
    for (int nt = 0; nt < 4; ++nt) {
      float4 bb = *(const float4*)(bp + q * 64 + nt * 16 + quad * 4);
      float4 mm = *(const float4*)(mp + q * 64 + nt * 16 + quad * 4);
      sv[nt * 4 + 0] = st[nt][mt][0] * 0.17677669529663687f + bb.x + mm.x;
      sv[nt * 4 + 1] = st[nt][mt][1] * 0.17677669529663687f + bb.y + mm.y;
      sv[nt * 4 + 2] = st[nt][mt][2] * 0.17677669529663687f + bb.z + mm.z;
      sv[nt * 4 + 3] = st[nt][mt][3] * 0.17677669529663687f + bb.w + mm.w;
    }
    float mx = sv[0];
    #pragma unroll
    for (int j = 1; j < 16; ++j) mx = fmaxf(mx, sv[j]);
    mx = fmaxf(mx, __shfl_xor(mx, 16));
    mx = fmaxf(mx, __shfl_xor(mx, 32));
    float sum = 0.f;
    #pragma unroll
    for (int j = 0; j < 16; ++j) { sv[j] = __expf(sv[j] - mx); sum += sv[j]; }
    sum += __shfl_xor(sum, 16);
    sum += __shfl_xor(sum, 32);
    float rinv = 1.0f / sum;
    #pragma unroll
    for (int nt = 0; nt < 4; ++nt) {
      union { unsigned short u[4]; uint2 v2; } o;
      #pragma unroll
      for (int rr = 0; rr < 4; ++rr) o.u[rr] = f2bf(sv[nt * 4 + rr] * rinv);
      int chunk = nt * 2 + (quad >> 1);
      *(uint2*)(qpb + q * 128 + ((chunk ^ (m15 & 7)) << 4) + (quad & 1) * 8) = o.v2;
    }
  }

  // ---- O^T = V^T P^T : lane holds token = m15, 4 dims -> 8B store ----
  #pragma unroll
  for (int tt = 0; tt < 4; ++tt) {
    bf16x8 pf[2];
    #pragma unroll
    for (int kt = 0; kt < 2; ++kt) {
      int row = tt * 16 + m15;
      pf[kt] = *(const bf16x8*)(qpb + row * 128 + (((kt * 4 + quad) ^ (m15 & 7)) << 4));
    }
    #pragma unroll
    for (int dt = 0; dt < 2; ++dt) {
      f32x4 acc = fz;
      #pragma unroll
      for (int kt = 0; kt < 2; ++kt) {
        bf16x8 vf = *(const bf16x8*)(vpb + (dt * 16 + m15) * 128 + (((kt * 4 + quad) ^ (m15 & 7)) << 4));
        acc = __builtin_amdgcn_mfma_f32_16x16x32_bf16(vf, pf[kt], acc, 0, 0, 0);
      }
      int row = tt * 16 + m15;
      union { unsigned short u[4]; uint2 v2; } o;
      #pragma unroll
      for (int rr = 0; rr < 4; ++rr) o.u[rr] = f2bf(acc[rr]);
      int chunk = dt * 2 + (quad >> 1);
      *(uint2*)(qpb + row * 64 + ((chunk ^ ((row >> 1) & 3)) << 4) + (quad & 1) * 8) = o.v2;
    }
  }
  __syncthreads();

  // ---- proj: swapped mfma(W,O) -> 8B global stores ----
  bf16x8 of[4][4];
  #pragma unroll
  for (int mt = 0; mt < 4; ++mt) {
    int row = mt * 16 + m15;
    int sw = ((row >> 1) & 3) << 4;
    #pragma unroll
    for (int kt = 0; kt < 4; ++kt)
      of[mt][kt] = *(const bf16x8*)(smem + kt * 12288 + row * 64 + ((quad << 4) ^ sw));
  }
  int pixo[4];
  #pragma unroll
  for (int mt = 0; mt < 4; ++mt) {
    int token = mt * 16 + m15;
    int ii = token / 7, jj = token - ii * 7;
    int gh = wh * 7 + ii + 3; if (gh >= 112) gh -= 112;   // reverse roll
    int gw = ww * 7 + jj + 3; if (gw >= 112) gw -= 112;
    pixo[mt] = gh * 112 + gw;
  }
  const size_t obase = (size_t)b * 1605632;
  #pragma unroll
  for (int sp = 0; sp < 2; ++sp) {
    int ct = 2 * h + sp;
    bf16x8 wf[4];
    #pragma unroll
    for (int kt = 0; kt < 4; ++kt)
      wf[kt] = *(const bf16x8*)(projw + (ct * 16 + m15) * 128 + kt * 32 + quad * 8);
    float4 pb4 = *(const float4*)(projb + ct * 16 + quad * 4);
    #pragma unroll
    for (int mt = 0; mt < 4; ++mt) {
      f32x4 acc = fz;
      #pragma unroll
      for (int kt = 0; kt < 4; ++kt)
        acc = __builtin_amdgcn_mfma_f32_16x16x32_bf16(wf[kt], of[mt][kt], acc, 0, 0, 0);
      int token = mt * 16 + m15;
      if (token < 49) {
        union { unsigned short u[4]; uint2 v2; } o;
        o.u[0] = f2bf(acc[0] + pb4.x); o.u[1] = f2bf(acc[1] + pb4.y);
        o.u[2] = f2bf(acc[2] + pb4.z); o.u[3] = f2bf(acc[3] + pb4.w);
        *(uint2*)(yw + obase + (size_t)pixo[mt] * 128 + ct * 16 + quad * 4) = o.v2;
      }
    }
  }
}

// ---------------------------------------------------------------------------
// Kernel 3: yws (B,H,W,C) bf16 + shortcut x (B,C,H,W) fp32 -> out fp32 NCHW
// LDS layout [16 c-chunks][112 w][8 ch] (chunk-row stride 1808B):
//   stores are uint4 (conflict-free), reads scalar (conflict-free)
// ---------------------------------------------------------------------------
__global__ __launch_bounds__(256) void k_out(const unsigned short* __restrict__ yws,
                                             const float* __restrict__ x,
                                             float* __restrict__ out) {
  __shared__ __attribute__((aligned(16))) char T[28928];
  int tid = threadIdx.x;
  int bid = blockIdx.x;
  int b = bid / 112;
  int hh = bid - b * 112;
  const unsigned short* src = yws + (size_t)(b * 112 + hh) * 14336;
  #pragma unroll
  for (int it = 0; it < 7; ++it) {
    int cc = tid + it * 256;                 // 1792 chunks of 8 channels
    int w = cc >> 4, ci = cc & 15;
    *(uint4*)(T + ci * 1808 + w * 16) = *(const uint4*)(src + w * 128 + ci * 8);
  }
  __syncthreads();
  int c = tid >> 1, half = tid & 1;
  const char* tr = T + (c >> 3) * 1808 + (c & 7) * 2;
  size_t rowoff = ((size_t)(b * 128 + c) * 112 + hh) * 112;
  const float* xr = x + rowoff;
  float* outr = out + rowoff;
  #pragma unroll
  for (int s2 = 0; s2 < 7; ++s2) {
    int w = half * 56 + s2 * 8;
    float4 xa = *(const float4*)(xr + w);
    float4 xb = *(const float4*)(xr + w + 4);
    float4 oa, ob;
    oa.x = bf2f(*(const unsigned short*)(tr + (w + 0) * 16)) + xa.x;
    oa.y = bf2f(*(const unsigned short*)(tr + (w + 1) * 16)) + xa.y;
    oa.z = bf2f(*(const unsigned short*)(tr + (w + 2) * 16)) + xa.z;
    oa.w = bf2f(*(const unsigned short*)(tr + (w + 3) * 16)) + xa.w;
    ob.x = bf2f(*(const unsigned short*)(tr + (w + 4) * 16)) + xb.x;
    ob.y = bf2f(*(const unsigned short*)(tr + (w + 5) * 16)) + xb.y;
    ob.z = bf2f(*(const unsigned short*)(tr + (w + 6) * 16)) + xb.z;
    ob.w = bf2f(*(const unsigned short*)(tr + (w + 7) * 16)) + xb.w;
    *(float4*)(outr + w) = oa;
    *(float4*)(outr + w + 4) = ob;
  }
}

// ---------------------------------------------------------------------------
extern "C" void kernel_launch(void* const* d_in, const int* in_sizes, int n_in,
                              void* d_out, int out_size, void* d_ws, size_t ws_size,
                              hipStream_t stream) {
  const float* x     = (const float*)d_in[0];
  const float* nw    = (const float*)d_in[1];
  const float* nb    = (const float*)d_in[2];
  const float* qkvw  = (const float*)d_in[3];
  const float* qkvb  = (const float*)d_in[4];
  const float* projw = (const float*)d_in[5];
  const float* projb = (const float*)d_in[6];
  const float* bt    = (const float*)d_in[7];
  const int*   ri    = (const int*)d_in[8];
  const float* am    = (const float*)d_in[9];

  unsigned short* xw   = (unsigned short*)d_ws;                        // 102,760,448 B
  unsigned short* yws  = (unsigned short*)((char*)d_ws + 102760448);   // 102,760,448 B
  float*          bp   = (float*)((char*)d_ws + 205520896);            //      65,536 B
  float*          mp   = (float*)((char*)d_ws + 205586432);            //   4,194,304 B
  unsigned short* qwbf = (unsigned short*)((char*)d_ws + 209780736);   //      98,304 B
  unsigned short* pwbf = (unsigned short*)((char*)d_ws + 209879040);   //      32,768 B
  float* out = (float*)d_out;

  k_prep<<<64,   256, 0, stream>>>(qkvw, projw, qwbf, pwbf);
  k_bias<<<64,   256, 0, stream>>>(bt, ri, bp);
  k_mask<<<4096, 256, 0, stream>>>(am, mp);
  k_ln  <<<1568, 256, 0, stream>>>(x, nw, nb, xw);
  k_attn<<<8192, 256, 0, stream>>>(xw, qwbf, qkvb, pwbf, projb, bp, mp, yws);
  k_out <<<3584, 256, 0, stream>>>(yws, x, out);
}